// Round 7
// baseline (180.478 us; speedup 1.0000x reference)
//
#include <hip/hip_runtime.h>
#include <hip/hip_bf16.h>

#define SS 2048
#define DD 512
#define HWIN 128

typedef __bf16 bf16x8 __attribute__((ext_vector_type(8)));
typedef unsigned short u16x8 __attribute__((ext_vector_type(8)));
typedef float f32x4 __attribute__((ext_vector_type(4)));

__device__ __forceinline__ unsigned short f2bf(float x) {
    unsigned u = __builtin_bit_cast(unsigned, x);
    return (unsigned short)((u + 0x7fffu + ((u >> 16) & 1u)) >> 16);
}
__device__ __forceinline__ float bf2f(unsigned short s) {
    unsigned u = ((unsigned)s) << 16;
    return __builtin_bit_cast(float, u);
}
__device__ __forceinline__ void split_bf(float x, unsigned short& h, unsigned short& l) {
    h = f2bf(x);
    l = f2bf(x - bf2f(h));
}
__device__ __forceinline__ void split8(float4 f0, float4 f1, u16x8& h, u16x8& l) {
    const float vals[8] = {f0.x, f0.y, f0.z, f0.w, f1.x, f1.y, f1.z, f1.w};
    #pragma unroll
    for (int i = 0; i < 8; ++i) {
        unsigned short hh, ll;
        split_bf(vals[i], hh, ll);
        h[i] = hh;
        l[i] = ll;
    }
}
__device__ __forceinline__ f32x4 mfma16(u16x8 a, u16x8 b, f32x4 c) {
    return __builtin_amdgcn_mfma_f32_16x16x32_bf16(
        __builtin_bit_cast(bf16x8, a), __builtin_bit_cast(bf16x8, b), c, 0, 0, 0);
}

// ---------------------------------------------------------------------------
// Cast all fp32 operands -> paired hi/lo bf16 ("paired": for each 8-elt chunk
// at elt offset e (multiple of 8), hi8 at u16 offset 2e, lo8 at 2e+8).
//   chunks 0..6291456:        q,k,v      -> AP   (24 MB)
//   chunks 6291456..7077888:  Wq,Wk,Wv   -> WP   (3 MB)
//   chunks 7077888..7340032:  Wo         -> WoP  (1 MB)
// ---------------------------------------------------------------------------
__global__ __launch_bounds__(256) void cast_pairs(
    const float* __restrict__ q, const float* __restrict__ k, const float* __restrict__ v,
    const float* __restrict__ wq, const float* __restrict__ wk,
    const float* __restrict__ wv, const float* __restrict__ wo,
    unsigned short* __restrict__ AP, unsigned short* __restrict__ WP,
    unsigned short* __restrict__ WoP)
{
    const size_t e0 = ((size_t)blockIdx.x * 256 + threadIdx.x) * 8;
    const float* src; size_t off; unsigned short* dst;
    if      (e0 < 2097152) { src = q;  off = e0;           dst = AP + 2 * e0; }
    else if (e0 < 4194304) { src = k;  off = e0 - 2097152; dst = AP + 2 * e0; }
    else if (e0 < 6291456) { src = v;  off = e0 - 4194304; dst = AP + 2 * e0; }
    else if (e0 < 6553600) { src = wq; off = e0 - 6291456; dst = WP + 2 * (e0 - 6291456); }
    else if (e0 < 6815744) { src = wk; off = e0 - 6553600; dst = WP + 2 * (e0 - 6291456); }
    else if (e0 < 7077888) { src = wv; off = e0 - 6815744; dst = WP + 2 * (e0 - 6291456); }
    else                   { src = wo; off = e0 - 7077888; dst = WoP + 2 * (e0 - 7077888); }
    u16x8 h, l;
    split8(*(const float4*)(src + off), *(const float4*)(src + off + 4), h, l);
    *(u16x8*)(dst)     = h;
    *(u16x8*)(dst + 8) = l;
}

// ---------------------------------------------------------------------------
// Split-bf16 GEMM: C = A @ W.T + bias, M=4096 N=512 K=512.
// A: paired hi/lo bf16 (AP) or separate hi/lo arrays (XH/XL). B: paired.
// 3-product bf16x3: AhWh + AhWl + AlWh. No fp32 splits in the K-loop.
// Block 256 thr / 4 waves; tile 128x64; wave 64x32 (4x2 MFMA 16x16x32).
// ---------------------------------------------------------------------------
template <bool A_PAIRED, bool OUT_SPLIT>
__device__ __forceinline__ void gemm_split_body(
    const unsigned short* __restrict__ Ap,
    const unsigned short* __restrict__ AHg, const unsigned short* __restrict__ ALg,
    const unsigned short* __restrict__ Wp, const float* __restrict__ bias,
    unsigned short* __restrict__ OH, unsigned short* __restrict__ OL,
    float* __restrict__ OF, int m0, int n0)
{
    constexpr int K = 512, N = 512;
    __shared__ unsigned short Ah[8 * 64 * 8], Al[8 * 64 * 8];
    __shared__ unsigned short Bh[4 * 64 * 8], Bl[4 * 64 * 8];

    const int tid = threadIdx.x, wave = tid >> 6, lane = tid & 63;
    const int lm = lane & 15, lq = lane >> 4;
    const int wm = wave >> 1, wn = wave & 1;

    f32x4 acc[4][2] = {};

    const int ar0 = m0 + (wave * 2 + 0) * 16 + lm;
    const int ar1 = m0 + (wave * 2 + 1) * 16 + lm;
    const int br  = n0 + wave * 16 + lm;
    const int kb  = lq * 8;

    unsigned short* aD0h = &Ah[((wave * 2 + 0) * 64 + lane) * 8];
    unsigned short* aD1h = &Ah[((wave * 2 + 1) * 64 + lane) * 8];
    unsigned short* aD0l = &Al[((wave * 2 + 0) * 64 + lane) * 8];
    unsigned short* aD1l = &Al[((wave * 2 + 1) * 64 + lane) * 8];
    unsigned short* bDh  = &Bh[(wave * 64 + lane) * 8];
    unsigned short* bDl  = &Bl[(wave * 64 + lane) * 8];

    for (int k0 = 0; k0 < K; k0 += 32) {
        u16x8 a0h, a0l, a1h, a1l, b0h, b0l;
        if (A_PAIRED) {
            const unsigned short* p0 = Ap + 2 * ((size_t)ar0 * K + k0 + kb);
            a0h = *(const u16x8*)p0;
            a0l = *(const u16x8*)(p0 + 8);
            const unsigned short* p1 = Ap + 2 * ((size_t)ar1 * K + k0 + kb);
            a1h = *(const u16x8*)p1;
            a1l = *(const u16x8*)(p1 + 8);
        } else {
            a0h = *(const u16x8*)(AHg + (size_t)ar0 * K + k0 + kb);
            a0l = *(const u16x8*)(ALg + (size_t)ar0 * K + k0 + kb);
            a1h = *(const u16x8*)(AHg + (size_t)ar1 * K + k0 + kb);
            a1l = *(const u16x8*)(ALg + (size_t)ar1 * K + k0 + kb);
        }
        {
            const unsigned short* pw = Wp + 2 * ((size_t)br * K + k0 + kb);
            b0h = *(const u16x8*)pw;
            b0l = *(const u16x8*)(pw + 8);
        }
        __syncthreads();                 // previous iteration's frag reads done
        *(u16x8*)aD0h = a0h; *(u16x8*)aD0l = a0l;
        *(u16x8*)aD1h = a1h; *(u16x8*)aD1l = a1l;
        *(u16x8*)bDh  = b0h; *(u16x8*)bDl  = b0l;
        __syncthreads();

        u16x8 afh[4], afl[4], bfh[2], bfl[2];
        #pragma unroll
        for (int i = 0; i < 4; ++i) {
            afh[i] = *(const u16x8*)&Ah[((wm * 4 + i) * 64 + lane) * 8];
            afl[i] = *(const u16x8*)&Al[((wm * 4 + i) * 64 + lane) * 8];
        }
        #pragma unroll
        for (int j = 0; j < 2; ++j) {
            bfh[j] = *(const u16x8*)&Bh[((wn * 2 + j) * 64 + lane) * 8];
            bfl[j] = *(const u16x8*)&Bl[((wn * 2 + j) * 64 + lane) * 8];
        }
        #pragma unroll
        for (int i = 0; i < 4; ++i)
            #pragma unroll
            for (int j = 0; j < 2; ++j) {
                acc[i][j] = mfma16(afh[i], bfh[j], acc[i][j]);
                acc[i][j] = mfma16(afh[i], bfl[j], acc[i][j]);
                acc[i][j] = mfma16(afl[i], bfh[j], acc[i][j]);
            }
    }

    #pragma unroll
    for (int i = 0; i < 4; ++i)
        #pragma unroll
        for (int j = 0; j < 2; ++j) {
            const int col = n0 + (wn * 2 + j) * 16 + lm;
            const float bv = bias[col];
            #pragma unroll
            for (int r = 0; r < 4; ++r) {
                const int row = m0 + (wm * 4 + i) * 16 + lq * 4 + r;
                const float v = acc[i][j][r] + bv;
                if (OUT_SPLIT) {
                    unsigned short h, l;
                    split_bf(v, h, l);
                    OH[(size_t)row * N + col] = h;
                    OL[(size_t)row * N + col] = l;
                } else {
                    OF[(size_t)row * N + col] = v;
                }
            }
        }
}

// 1D grid 768 with XCD swizzle: d = 64*(g/8) + 8x + (g%8), g = y*3+z.
// All 8 x-siblings (same A rows) share residue mod 8 -> same XCD L2.
__global__ __launch_bounds__(256) void proj_gemm(
    const unsigned short* __restrict__ AP, const unsigned short* __restrict__ WP,
    const float* __restrict__ bq, const float* __restrict__ bk, const float* __restrict__ bv,
    unsigned short* __restrict__ base)
{
    const int d = blockIdx.x;
    const int hi = d >> 6, low = d & 63;
    const int x = low >> 3, r = low & 7;
    const int g = hi * 8 + r;            // 0..95
    const int y = g / 3, z = g - y * 3;

    const unsigned short* Ap = AP + (size_t)z * 4194304;
    const unsigned short* Wp = WP + (size_t)z * 524288;
    const float* bias = (z == 0) ? bq : ((z == 1) ? bk : bv);
    unsigned short* OH = base + (size_t)z * 4194304;
    unsigned short* OL = OH + 2097152;
    gemm_split_body<true, true>(Ap, nullptr, nullptr, Wp, bias,
                                OH, OL, nullptr, y * 128, x * 64);
}

// 1D grid 256 with XCD swizzle: d = 64*(y/8) + 8x + (y%8).
__global__ __launch_bounds__(256) void out_gemm(
    const unsigned short* __restrict__ XH, const unsigned short* __restrict__ XL,
    const unsigned short* __restrict__ WoP, const float* __restrict__ bo,
    float* __restrict__ O)
{
    const int d = blockIdx.x;
    const int hi = d >> 6, low = d & 63;
    const int x = low >> 3, r = low & 7;
    const int y = hi * 8 + r;            // 0..31
    gemm_split_body<false, false>(nullptr, XH, XL, WoP, bo,
                                  nullptr, nullptr, O, y * 128, x * 64);
}

// ---------------------------------------------------------------------------
// V column sums, two-stage.
// ---------------------------------------------------------------------------
__global__ __launch_bounds__(256) void vsum_stage1(
    const unsigned short* __restrict__ VH, const unsigned short* __restrict__ VL,
    float* __restrict__ partial)
{
    const int bh = blockIdx.x, c = blockIdx.y;
    const int h = bh & 7, b = bh >> 3;
    const int t = threadIdx.x, d = t & 63, g = t >> 6;
    __shared__ float p[4][64];
    const size_t base = ((size_t)b * SS + c * 64) * DD + (size_t)h * 64 + d;
    float acc = 0.f;
    #pragma unroll 4
    for (int s = g; s < 64; s += 4) {
        const size_t ix = base + (size_t)s * DD;
        acc += bf2f(VH[ix]) + bf2f(VL[ix]);
    }
    p[g][d] = acc;
    __syncthreads();
    if (t < 64)
        partial[((size_t)bh * 32 + c) * 64 + t] =
            p[0][t] + p[1][t] + p[2][t] + p[3][t];
}

__global__ __launch_bounds__(64) void vsum_stage2(
    const float* __restrict__ partial, float* __restrict__ VS)
{
    const int bh = blockIdx.x, d = threadIdx.x;
    float acc = 0.f;
    #pragma unroll 8
    for (int c = 0; c < 32; ++c)
        acc += partial[((size_t)bh * 32 + c) * 64 + d];
    VS[bh * 64 + d] = acc;
}

// ---------------------------------------------------------------------------
// Split-bf16 MFMA sliding-window attention (unchanged from round 5/6):
//   x = [ sum_win (e^s - 1) v + VS ] / ( 2048 + sum_win (e^s - 1) )
// ---------------------------------------------------------------------------
__global__ __launch_bounds__(256) void attn_mfma(
    const unsigned short* __restrict__ QH, const unsigned short* __restrict__ QL,
    const unsigned short* __restrict__ KH, const unsigned short* __restrict__ KL,
    const unsigned short* __restrict__ VH, const unsigned short* __restrict__ VL,
    const float* __restrict__ VS,
    unsigned short* __restrict__ XH, unsigned short* __restrict__ XL)
{
    const int dblk = blockIdx.x;
    const int bhi = dblk >> 8, blow = dblk & 255;
    const int xblk = blow >> 3, rr = blow & 7;
    const int bh = bhi * 8 + rr;         // 0..15
    const int h = bh & 7, b = bh >> 3;
    const int i0 = xblk * 64;
    const int tid = threadIdx.x, wave = tid >> 6, lane = tid & 63;
    const int lm = lane & 15, lq = lane >> 4;
    const int kb = lq * 8;

    __shared__ unsigned short Kth[64][72], Ktl[64][72];   // [j][d]
    __shared__ unsigned short Vth[64][72], Vtl[64][72];   // [d][j] transposed
    __shared__ unsigned short Swh[64][72], Swl[64][72];   // [q][j]

    const size_t qoff = ((size_t)(b * SS + i0 + wave * 16 + lm)) * DD + h * 64 + kb;
    const u16x8 aQ0h = *(const u16x8*)(QH + qoff);
    const u16x8 aQ0l = *(const u16x8*)(QL + qoff);
    const u16x8 aQ1h = *(const u16x8*)(QH + qoff + 32);
    const u16x8 aQ1l = *(const u16x8*)(QL + qoff + 32);

    f32x4 oacc[4] = {};
    float dacc[4] = {0.f, 0.f, 0.f, 0.f};

    const int sr = tid & 63, sc = (tid >> 6) * 16;

    for (int jt = 0; jt < 5; ++jt) {
        const int jt0 = i0 - 128 + jt * 64;
        {
            const int j = jt0 + sr;
            u16x8 z = {0,0,0,0,0,0,0,0};
            u16x8 kh0 = z, kh1 = z, kl0 = z, kl1 = z;
            u16x8 vh0 = z, vh1 = z, vl0 = z, vl1 = z;
            if (j >= 0 && j < SS) {
                const size_t gb = ((size_t)(b * SS + j)) * DD + h * 64 + sc;
                kh0 = *(const u16x8*)(KH + gb); kh1 = *(const u16x8*)(KH + gb + 8);
                kl0 = *(const u16x8*)(KL + gb); kl1 = *(const u16x8*)(KL + gb + 8);
                vh0 = *(const u16x8*)(VH + gb); vh1 = *(const u16x8*)(VH + gb + 8);
                vl0 = *(const u16x8*)(VL + gb); vl1 = *(const u16x8*)(VL + gb + 8);
            }
            *(u16x8*)&Kth[sr][sc]     = kh0; *(u16x8*)&Kth[sr][sc + 8] = kh1;
            *(u16x8*)&Ktl[sr][sc]     = kl0; *(u16x8*)&Ktl[sr][sc + 8] = kl1;
            #pragma unroll
            for (int cc = 0; cc < 8; ++cc) {
                Vth[sc + cc][sr] = vh0[cc]; Vth[sc + 8 + cc][sr] = vh1[cc];
                Vtl[sc + cc][sr] = vl0[cc]; Vtl[sc + 8 + cc][sr] = vl1[cc];
            }
        }
        __syncthreads();

        #pragma unroll
        for (int js = 0; js < 4; ++js) {
            const int j0 = js * 16;
            const u16x8 bK0h = *(const u16x8*)&Kth[j0 + lm][kb];
            const u16x8 bK0l = *(const u16x8*)&Ktl[j0 + lm][kb];
            const u16x8 bK1h = *(const u16x8*)&Kth[j0 + lm][kb + 32];
            const u16x8 bK1l = *(const u16x8*)&Ktl[j0 + lm][kb + 32];
            f32x4 s = {0.f, 0.f, 0.f, 0.f};
            s = mfma16(aQ0h, bK0h, s);
            s = mfma16(aQ0h, bK0l, s);
            s = mfma16(aQ0l, bK0h, s);
            s = mfma16(aQ1h, bK1h, s);
            s = mfma16(aQ1h, bK1l, s);
            s = mfma16(aQ1l, bK1h, s);
            const int jg = jt0 + j0 + lm;
            const int iq = i0 + wave * 16 + lq * 4;
            #pragma unroll
            for (int r = 0; r < 4; ++r) {
                const int qi = iq + r;
                const bool in = (jg >= 0) && (jg < SS) &&
                                (jg >= qi - HWIN) && (jg <= qi + HWIN);
                const float w = in ? (__expf(s[r] * 0.125f) - 1.0f) : 0.0f;
                dacc[r] += w;
                unsigned short wh, wl;
                split_bf(w, wh, wl);
                Swh[wave * 16 + lq * 4 + r][j0 + lm] = wh;
                Swl[wave * 16 + lq * 4 + r][j0 + lm] = wl;
            }
        }
        __syncthreads();

        const u16x8 aP0h = *(const u16x8*)&Swh[wave * 16 + lm][kb];
        const u16x8 aP0l = *(const u16x8*)&Swl[wave * 16 + lm][kb];
        const u16x8 aP1h = *(const u16x8*)&Swh[wave * 16 + lm][kb + 32];
        const u16x8 aP1l = *(const u16x8*)&Swl[wave * 16 + lm][kb + 32];
        #pragma unroll
        for (int s4 = 0; s4 < 4; ++s4) {
            const u16x8 bV0h = *(const u16x8*)&Vth[s4 * 16 + lm][kb];
            const u16x8 bV0l = *(const u16x8*)&Vtl[s4 * 16 + lm][kb];
            const u16x8 bV1h = *(const u16x8*)&Vth[s4 * 16 + lm][kb + 32];
            const u16x8 bV1l = *(const u16x8*)&Vtl[s4 * 16 + lm][kb + 32];
            oacc[s4] = mfma16(aP0h, bV0h, oacc[s4]);
            oacc[s4] = mfma16(aP0l, bV0h, oacc[s4]);
            oacc[s4] = mfma16(aP0h, bV0l, oacc[s4]);
            oacc[s4] = mfma16(aP1h, bV1h, oacc[s4]);
            oacc[s4] = mfma16(aP1l, bV1h, oacc[s4]);
            oacc[s4] = mfma16(aP1h, bV1l, oacc[s4]);
        }
        __syncthreads();
    }

    #pragma unroll
    for (int r = 0; r < 4; ++r) {
        float v = dacc[r];
        v += __shfl_xor(v, 1);
        v += __shfl_xor(v, 2);
        v += __shfl_xor(v, 4);
        v += __shfl_xor(v, 8);
        dacc[r] = v + 2048.0f;
    }

    #pragma unroll
    for (int s4 = 0; s4 < 4; ++s4) {
        const float vsv = VS[bh * 64 + s4 * 16 + lm];
        #pragma unroll
        for (int r = 0; r < 4; ++r) {
            const int qrow = i0 + wave * 16 + lq * 4 + r;
            const float x = (oacc[s4][r] + vsv) / dacc[r];
            unsigned short xh, xl;
            split_bf(x, xh, xl);
            const size_t ix = ((size_t)(b * SS + qrow)) * DD + h * 64 + s4 * 16 + lm;
            XH[ix] = xh;
            XL[ix] = xl;
        }
    }
}

// ---------------------------------------------------------------------------
extern "C" void kernel_launch(void* const* d_in, const int* in_sizes, int n_in,
                              void* d_out, int out_size, void* d_ws, size_t ws_size,
                              hipStream_t stream)
{
    const float* query  = (const float*)d_in[0];
    const float* key_in = (const float*)d_in[1];
    const float* value  = (const float*)d_in[2];
    const float* Wq = (const float*)d_in[3]; const float* bq = (const float*)d_in[4];
    const float* Wk = (const float*)d_in[5]; const float* bk = (const float*)d_in[6];
    const float* Wv = (const float*)d_in[7]; const float* bv = (const float*)d_in[8];
    const float* Wo = (const float*)d_in[9]; const float* bo = (const float*)d_in[10];

    // ws layout (u16 offsets; harness poison-fill shows ws_size ~268 MB):
    //   0..12582912      QH QL KH KL VH VL  (proj outputs, split arrays)
    //   12582912         XH ; 14680064 XL   (attn outputs)
    //   16777216         AP  paired q,k,v   (12582912 u16 = 24 MB)
    //   29360128         WP  paired Wq,Wk,Wv (1572864 u16 = 3 MB)
    //   30932992         WoP paired Wo      (524288 u16 = 1 MB)
    //   byte 62914560    part (vsum partials, 128 KB)
    //   byte 63045632    VS (16*64 fp32)
    unsigned short* wsb = (unsigned short*)d_ws;
    unsigned short* QH = wsb;
    unsigned short* QL = wsb + 2097152;
    unsigned short* KH = wsb + 4194304;
    unsigned short* KL = wsb + 6291456;
    unsigned short* VH = wsb + 8388608;
    unsigned short* VL = wsb + 10485760;
    unsigned short* XH = wsb + 12582912;
    unsigned short* XL = wsb + 14680064;
    unsigned short* AP  = wsb + 16777216;
    unsigned short* WP  = wsb + 29360128;
    unsigned short* WoP = wsb + 30932992;
    float* part = (float*)((char*)d_ws + 62914560);
    float* VSp  = (float*)((char*)d_ws + 63045632);

    cast_pairs<<<3584, 256, 0, stream>>>(
        query, key_in, value, Wq, Wk, Wv, Wo, AP, WP, WoP);

    proj_gemm<<<768, 256, 0, stream>>>(AP, WP, bq, bk, bv, QH);

    vsum_stage1<<<dim3(16, 32), 256, 0, stream>>>(VH, VL, part);
    vsum_stage2<<<16, 64, 0, stream>>>(part, VSp);

    attn_mfma<<<512, 256, 0, stream>>>(
        QH, QL, KH, KL, VH, VL, VSp, XH, XL);

    out_gemm<<<256, 256, 0, stream>>>(XH, XL, WoP, bo, (float*)d_out);
}